// Round 7
// baseline (92.609 us; speedup 1.0000x reference)
//
#include <hip/hip_runtime.h>
#include <cstdint>
#include <cstddef>

typedef __bf16 bf16x8 __attribute__((ext_vector_type(8)));
typedef __bf16 bf16x2 __attribute__((ext_vector_type(2)));
typedef float f32x4 __attribute__((ext_vector_type(4)));
typedef unsigned short u16x2 __attribute__((ext_vector_type(2)));

constexpr int HH = 1024;   // hidden dim
constexpr int II = 1024;   // intermediate dim
constexpr int KMAX = 2;
constexpr int EMAX = 8;
constexpr int GU_TILES = 24;   // M=128 tiles: worst case 16+7
constexpr int DN_TILES = 40;   // M=64 tiles: worst case 32+7
constexpr float FALPHA = 1.702f;
constexpr float FLIMIT = 7.0f;

#if __has_builtin(__builtin_amdgcn_cvt_scalef32_pk_bf16_fp4)
#define USE_CVT 1
#else
#define USE_CVT 0
#endif

#define SCHED0() __builtin_amdgcn_sched_barrier(0)

// ---- fallback perm decode (k-order within 8-group permuted [0,2,4,6,1,3,5,7]) ----
__device__ __forceinline__ unsigned pk_add16(unsigned a, unsigned b) {
  u16x2 x, y;
  __builtin_memcpy(&x, &a, 4); __builtin_memcpy(&y, &b, 4);
  u16x2 r = x + y;
  unsigned o; __builtin_memcpy(&o, &r, 4); return o;
}
__device__ __forceinline__ int4 decode_chunk(int4 raw, unsigned addk) {
  unsigned p = (unsigned)raw.x | ((unsigned)raw.y << 8) |
               ((unsigned)raw.z << 16) | ((unsigned)raw.w << 24);
  unsigned q = p >> 4;
  unsigned me = p & 0x07070707u, mo = q & 0x07070707u;
  unsigned se = p & 0x08080808u, so = q & 0x08080808u;
  unsigned hiE = __builtin_amdgcn_perm(0x40404040u, 0x3F3F3F14u, me) | (se << 4);
  unsigned hiO = __builtin_amdgcn_perm(0x40404040u, 0x3F3F3F14u, mo) | (so << 4);
  unsigned loE = __builtin_amdgcn_perm(0xC0804000u, 0xC0800000u, me);
  unsigned loO = __builtin_amdgcn_perm(0xC0804000u, 0xC0800000u, mo);
  int4 out;
  out.x = (int)pk_add16(__builtin_amdgcn_perm(hiE, loE, 0x05010400u), addk);
  out.y = (int)pk_add16(__builtin_amdgcn_perm(hiE, loE, 0x07030602u), addk);
  out.z = (int)pk_add16(__builtin_amdgcn_perm(hiO, loO, 0x05010400u), addk);
  out.w = (int)pk_add16(__builtin_amdgcn_perm(hiO, loO, 0x07030602u), addk);
  return out;
}
__device__ __forceinline__ unsigned make_addk(int s) {
  int k = s - 127;
  unsigned t = ((unsigned)(k << 7)) & 0xFFFFu;
  return t | (t << 16);
}

// raw chunk (8 fp4 as int32-per-byte) + e8m0 scale -> bf16x8 fragment
__device__ __forceinline__ bf16x8 decode_frag(int4 raw, int s) {
#if USE_CVT
  unsigned t0 = __builtin_amdgcn_perm((unsigned)raw.y, (unsigned)raw.x, 0x00000400u);
  unsigned t1 = __builtin_amdgcn_perm((unsigned)raw.w, (unsigned)raw.z, 0x00000400u);
  unsigned p  = __builtin_amdgcn_perm(t1, t0, 0x05040100u);
  float scf = __uint_as_float((unsigned)s << 23);
  bf16x2 a = __builtin_amdgcn_cvt_scalef32_pk_bf16_fp4(p, scf, 0);
  bf16x2 b = __builtin_amdgcn_cvt_scalef32_pk_bf16_fp4(p, scf, 1);
  bf16x2 c = __builtin_amdgcn_cvt_scalef32_pk_bf16_fp4(p, scf, 2);
  bf16x2 d = __builtin_amdgcn_cvt_scalef32_pk_bf16_fp4(p, scf, 3);
  bf16x8 r;
  r[0]=a[0]; r[1]=a[1]; r[2]=b[0]; r[3]=b[1]; r[4]=c[0]; r[5]=c[1]; r[6]=d[0]; r[7]=d[1];
  return r;
#else
  int4 d4 = decode_chunk(raw, make_addk(s));
  bf16x8 r; __builtin_memcpy(&r, &d4, 16);
  return r;
#endif
}

__device__ __forceinline__ void gll16(const void* g, void* l) {
  __builtin_amdgcn_global_load_lds(
      (const __attribute__((address_space(1))) void*)g,
      (__attribute__((address_space(3))) void*)l, 16, 0, 0);
}

// ---------------- routing ----------------
__global__ void routing_kernel(const float* __restrict__ logits, const int* __restrict__ dk,
                               int T, int E, float* __restrict__ route,
                               int* __restrict__ tidx, float* __restrict__ tw) {
  int t = blockIdx.x * blockDim.x + threadIdx.x;
  if (t >= T) return;
  int kk = *dk; if (kk > KMAX) kk = KMAX; if (kk < 1) kk = 1;
  int EE = E > EMAX ? EMAX : E;
  float v[EMAX]; bool used[EMAX];
  for (int e = 0; e < EE; ++e) { v[e] = logits[t * E + e]; used[e] = false; route[t * E + e] = 0.f; }
  float tv[KMAX]; int ti[KMAX];
  for (int j = 0; j < kk; ++j) {
    float best = -3.4e38f; int bi = 0;
    for (int e = 0; e < EE; ++e) if (!used[e] && v[e] > best) { best = v[e]; bi = e; }
    used[bi] = true; tv[j] = best; ti[j] = bi;
  }
  float mx = tv[0], ssum = 0.f, wj[KMAX];
  for (int j = 0; j < kk; ++j) { wj[j] = __expf(tv[j] - mx); ssum += wj[j]; }
  for (int j = 0; j < kk; ++j) {
    float wv = wj[j] / ssum;
    route[t * E + ti[j]] = wv;
    tidx[t * kk + j] = ti[j];
    tw[t * kk + j] = wv;
  }
}

__global__ void build_lists(const int* __restrict__ tidx, const int* __restrict__ dk,
                            int T, int* __restrict__ lists, int* __restrict__ counts) {
  int e = blockIdx.x;
  int lane = threadIdx.x;
  int kk = *dk; if (kk > KMAX) kk = KMAX; if (kk < 1) kk = 1;
  int cnt = 0;
  for (int base = 0; base < T; base += 64) {
    int t = base + lane;
    int j = -1;
    if (t < T) {
      for (int q = 0; q < kk; ++q) if (tidx[t * kk + q] == e) j = q;
    }
    unsigned long long m = __ballot(j >= 0);
    if (j >= 0) {
      int pre = __popcll(m & ((1ull << lane) - 1ull));
      lists[e * T + cnt + pre] = (t << 3) | j;
    }
    cnt += __popcll(m);
  }
  if (lane == 0) counts[e] = cnt;
}

__global__ void build_tiles(const int* __restrict__ counts, int E,
                            int* __restrict__ tabGU, int* __restrict__ tabDN) {
  if (threadIdx.x == 0 && blockIdx.x == 0) {
    int g = 0, d = 0;
    for (int e = 0; e < E && e < EMAX; ++e) {
      int c = counts[e];
      for (int m = 0; m * 128 < c && g < GU_TILES; ++m) tabGU[g++] = (e << 16) | m;
      for (int m = 0; m * 64 < c && d < DN_TILES; ++m) tabDN[d++] = (e << 16) | m;
    }
    for (; g < GU_TILES; ++g) tabGU[g] = -1;
    for (; d < DN_TILES; ++d) tabDN[d] = -1;
  }
}

// ---------------- hs fp32 -> bf16 ----------------
__global__ void convert_hs(const float* __restrict__ hs, __bf16* __restrict__ hsb, int n8) {
  int g = blockIdx.x * 256 + threadIdx.x;
  if (g >= n8) return;
  const float4* p = (const float4*)hs + (size_t)g * 2;
  float4 a = p[0], b = p[1];
  bf16x8 r;
#if USE_CVT
  r[0] = (__bf16)a.x; r[1] = (__bf16)a.y; r[2] = (__bf16)a.z; r[3] = (__bf16)a.w;
  r[4] = (__bf16)b.x; r[5] = (__bf16)b.y; r[6] = (__bf16)b.z; r[7] = (__bf16)b.w;
#else
  r[0] = (__bf16)a.x; r[1] = (__bf16)a.z; r[2] = (__bf16)b.x; r[3] = (__bf16)b.z;
  r[4] = (__bf16)a.y; r[5] = (__bf16)a.w; r[6] = (__bf16)b.y; r[7] = (__bf16)b.w;
#endif
  *(bf16x8*)(hsb + (size_t)g * 8) = r;
}

// ================= gate+up GEMM =================
// M=128 slots, N=128 cols (64 i x {gate,up}), BK=64, 256 thr = 4 waves (2x2),
// wave tile 64x64 (fm=4, fn=4). Depth-2 counted-vmcnt pipeline, raw barriers.
__global__ __launch_bounds__(256, 2) void gemm_gate_up(
    const __bf16* __restrict__ hsb,
    const int* __restrict__ gblk, const int* __restrict__ gscl, const float* __restrict__ gbias,
    const int* __restrict__ ublk, const int* __restrict__ uscl, const float* __restrict__ ubias,
    const int* __restrict__ lists, const int* __restrict__ counts,
    const float* __restrict__ tw, const int* __restrict__ dk,
    const int* __restrict__ tab,
    __bf16* __restrict__ act, int T)
{
  int te = tab[blockIdx.x];
  if (te < 0) return;
  int e = te >> 16, mtile = te & 0xFFFF;
  int cnt = counts[e];
  int n_valid = cnt - mtile * 128;
  if (n_valid <= 0) return;
  if (n_valid > 128) n_valid = 128;
  int kk = *dk; if (kk > KMAX) kk = KMAX; if (kk < 1) kk = 1;

  __shared__ int s_tok[128];
  __shared__ __attribute__((aligned(16))) char Abuf[2][16384];  // [row][chunk^(row&7)]*16B
  __shared__ __attribute__((aligned(16))) char Braw[2][16384];  // raw fp4-inflated, same swizzle
  __shared__ __attribute__((aligned(8))) unsigned short sScl[2][64][36]; // [mat][i_loc][kblk] pad->36

  int tid = threadIdx.x;
  if (tid < 128) {
    int idx = mtile * 128 + tid;
    s_tok[tid] = lists[e * T + (idx < cnt ? idx : mtile * 128)];
  }
  __syncthreads();

  int lane = tid & 63, w = tid >> 6;
  int r15 = lane & 15, kg = lane >> 4;
  int wr = w >> 1, wc = w & 1;
  int cA = (lane & 7) ^ (lane >> 3);
  int ibase = blockIdx.y * 64;

  // A staging: wave w stages rows w*32 + q*8 + (lane>>3), q=0..3
  unsigned aOff[4];
  #pragma unroll
  for (int q = 0; q < 4; ++q) {
    int row = w * 32 + q * 8 + (lane >> 3);
    int tok = s_tok[row] >> 3;
    aOff[q] = (unsigned)tok * (HH * 2) + (unsigned)cA * 16;
  }
  // B staging: rows w*32 + q*8 + (lane>>3); row -> mat=(row>>4)&1, i=ibase+((row>>5)<<4)+(row&15)
  const char* bSrc[4];
  #pragma unroll
  for (int q = 0; q < 4; ++q) {
    int row = w * 32 + q * 8 + (lane >> 3);
    int mat = (row >> 4) & 1;
    int i = ibase + ((row >> 5) << 4) + (row & 15);
    const int* base = mat ? ublk : gblk;
    bSrc[q] = (const char*)(base + ((size_t)e * II + i) * (HH / 2)) + cA * 16;
  }

  // stage both pipeline batches (t=0 -> buf0, t=1 -> buf1)
  #pragma unroll
  for (int q = 0; q < 4; ++q) {
    gll16((const char*)hsb + aOff[q], Abuf[0] + (w * 32 + q * 8) * 128);
    gll16(bSrc[q], Braw[0] + (w * 32 + q * 8) * 128);
  }
  #pragma unroll
  for (int q = 0; q < 4; ++q) {
    gll16((const char*)hsb + aOff[q] + 128, Abuf[1] + (w * 32 + q * 8) * 128);
    gll16(bSrc[q] + 128, Braw[1] + (w * 32 + q * 8) * 128);
  }

  // scale table: 2 segments x 64 rows x 8 int4-chunks = 1024 transactions -> u16 LDS
  for (int idx = tid; idx < 1024; idx += 256) {
    int sgm = idx >> 9, rem = idx & 511;
    int row = rem >> 3, c4 = rem & 7;
    const int* base = sgm ? uscl : gscl;
    int4 v = *((const int4*)(base + ((size_t)e * II + ibase + row) * 32) + c4);
    unsigned short* dst = &sScl[sgm][row][c4 * 4];
    dst[0] = (unsigned short)v.x; dst[1] = (unsigned short)v.y;
    dst[2] = (unsigned short)v.z; dst[3] = (unsigned short)v.w;
  }
  __syncthreads();   // full drain once (prologue)

  f32x4 acc[4][4];
  #pragma unroll
  for (int a = 0; a < 4; ++a)
    #pragma unroll
    for (int b = 0; b < 4; ++b) acc[a][b] = (f32x4)0.f;

  constexpr int NK = HH / 64;  // 16
  #pragma unroll 1
  for (int t = 0; t < NK; ++t) {
    if (t > 0) {
      if (t < NK - 1) { asm volatile("s_waitcnt vmcnt(8)" ::: "memory"); }
      else            { asm volatile("s_waitcnt vmcnt(0)" ::: "memory"); }
      SCHED0();
      __builtin_amdgcn_s_barrier();   // batch t visible to all waves
      SCHED0();
    }
    const char* Ac = Abuf[t & 1];
    const char* Bc = Braw[t & 1];
    // per-lane scales for this K-step (u16 pair: kblk 2t, 2t+1)
    unsigned sv[4];
    #pragma unroll
    for (int fn = 0; fn < 4; ++fn) {
      int mat = fn & 1;
      int il = (wc * 2 + (fn >> 1)) * 16 + r15;
      sv[fn] = *(const unsigned*)((const char*)sScl + (mat * 64 + il) * 72 + t * 4);
    }
    #pragma unroll
    for (int kq = 0; kq < 2; ++kq) {
      int kc = kq * 4 + kg;
      bf16x8 bfr[4];
      #pragma unroll
      for (int fn = 0; fn < 4; ++fn) {
        int n = wc * 64 + fn * 16 + r15;
        int4 raw = *(const int4*)(Bc + n * 128 + ((kc ^ (n & 7)) << 4));
        int s = kq ? (int)(sv[fn] >> 16) : (int)(sv[fn] & 0xFFFF);
        bfr[fn] = decode_frag(raw, s);
      }
      #pragma unroll
      for (int fm = 0; fm < 4; ++fm) {
        int m = wr * 64 + fm * 16 + r15;
        bf16x8 af = *(const bf16x8*)(Ac + m * 128 + ((kc ^ (m & 7)) << 4));
        #pragma unroll
        for (int fn = 0; fn < 4; ++fn)
          acc[fm][fn] = __builtin_amdgcn_mfma_f32_16x16x32_bf16(af, bfr[fn], acc[fm][fn], 0, 0, 0);
      }
    }
    if (t + 2 < NK) {
      asm volatile("s_waitcnt lgkmcnt(0)" ::: "memory");
      SCHED0();
      __builtin_amdgcn_s_barrier();   // all waves done reading buf[t&1]
      SCHED0();
      char* An = Abuf[t & 1];
      char* Bn = Braw[t & 1];
      #pragma unroll
      for (int q = 0; q < 4; ++q) {
        gll16((const char*)hsb + aOff[q] + (t + 2) * 128, An + (w * 32 + q * 8) * 128);
        gll16(bSrc[q] + (t + 2) * 128, Bn + (w * 32 + q * 8) * 128);
      }
    }
  }

  // epilogue: pairs (2p, 2p+1) = (gate, up) for i = ibase + wc*32 + p*16 + r15
  #pragma unroll
  for (int p = 0; p < 2; ++p) {
    int i_log = ibase + wc * 32 + p * 16 + r15;
    float gb = gbias[e * II + i_log], ub = ubias[e * II + i_log];
#if USE_CVT
    int i_st = i_log;
#else
    int i_st = (i_log & ~7) | ((i_log & 1) << 2) | ((i_log & 7) >> 1);
#endif
    #pragma unroll
    for (int fm = 0; fm < 4; ++fm) {
      #pragma unroll
      for (int rg = 0; rg < 4; ++rg) {
        int mloc = wr * 64 + fm * 16 + kg * 4 + rg;
        if (mloc < n_valid) {
          int entry = s_tok[mloc];
          int t2 = entry >> 3, j = entry & 7;
          float wv = tw[t2 * kk + j];
          float g = fminf(acc[fm][p * 2][rg] + gb, FLIMIT);
          float u = fminf(fmaxf(acc[fm][p * 2 + 1][rg] + ub, -FLIMIT), FLIMIT);
          float glu = g / (1.f + __expf(-FALPHA * g));
          act[((size_t)t2 * kk + j) * II + i_st] = (__bf16)((u + 1.f) * glu * wv);
        }
      }
    }
  }
}

// ================= down GEMM =================
// M=64 slots, N=128 h, BK=64, 256 thr = 4 waves (2x2), wave tile 32x64 (fm=2, fn=4).
__global__ __launch_bounds__(256, 2) void gemm_down(
    const __bf16* __restrict__ act,
    const int* __restrict__ dblk, const int* __restrict__ dscl,
    const int* __restrict__ lists, const int* __restrict__ counts,
    const int* __restrict__ dk, const int* __restrict__ tab,
    __bf16* __restrict__ partial, int T)
{
  int te = tab[blockIdx.x];
  if (te < 0) return;
  int e = te >> 16, mtile = te & 0xFFFF;
  int cnt = counts[e];
  int n_valid = cnt - mtile * 64;
  if (n_valid <= 0) return;
  if (n_valid > 64) n_valid = 64;
  int kk = *dk; if (kk > KMAX) kk = KMAX; if (kk < 1) kk = 1;

  __shared__ int s_tok[64];
  __shared__ __attribute__((aligned(16))) char Abuf[2][8192];
  __shared__ __attribute__((aligned(16))) char Braw[2][16384];
  __shared__ __attribute__((aligned(8))) unsigned short sScl[128][36];

  int tid = threadIdx.x;
  if (tid < 64) {
    int idx = mtile * 64 + tid;
    s_tok[tid] = lists[e * T + (idx < cnt ? idx : mtile * 64)];
  }
  __syncthreads();

  int lane = tid & 63, w = tid >> 6;
  int r15 = lane & 15, kg = lane >> 4;
  int wr = w >> 1, wc = w & 1;
  int cA = (lane & 7) ^ (lane >> 3);
  int hbase = blockIdx.y * 128;

  unsigned aOff[2];
  #pragma unroll
  for (int q = 0; q < 2; ++q) {
    int row = w * 16 + q * 8 + (lane >> 3);
    int entry = s_tok[row];
    unsigned slot = (unsigned)(entry >> 3) * kk + (entry & 7);
    aOff[q] = slot * (II * 2) + (unsigned)cA * 16;
  }
  const char* bSrc[4];
  #pragma unroll
  for (int q = 0; q < 4; ++q) {
    int row = w * 32 + q * 8 + (lane >> 3);
    int h = hbase + row;
    bSrc[q] = (const char*)(dblk + ((size_t)e * HH + h) * (II / 2)) + cA * 16;
  }

  #pragma unroll
  for (int q = 0; q < 2; ++q)
    gll16((const char*)act + aOff[q], Abuf[0] + (w * 16 + q * 8) * 128);
  #pragma unroll
  for (int q = 0; q < 4; ++q)
    gll16(bSrc[q], Braw[0] + (w * 32 + q * 8) * 128);
  #pragma unroll
  for (int q = 0; q < 2; ++q)
    gll16((const char*)act + aOff[q] + 128, Abuf[1] + (w * 16 + q * 8) * 128);
  #pragma unroll
  for (int q = 0; q < 4; ++q)
    gll16(bSrc[q] + 128, Braw[1] + (w * 32 + q * 8) * 128);

  for (int idx = tid; idx < 1024; idx += 256) {
    int row = idx >> 3, c4 = idx & 7;
    int4 v = *((const int4*)(dscl + ((size_t)e * HH + hbase + row) * 32) + c4);
    unsigned short* dst = &sScl[row][c4 * 4];
    dst[0] = (unsigned short)v.x; dst[1] = (unsigned short)v.y;
    dst[2] = (unsigned short)v.z; dst[3] = (unsigned short)v.w;
  }
  __syncthreads();

  f32x4 acc[2][4];
  #pragma unroll
  for (int a = 0; a < 2; ++a)
    #pragma unroll
    for (int b = 0; b < 4; ++b) acc[a][b] = (f32x4)0.f;

  constexpr int NK = II / 64;  // 16
  #pragma unroll 1
  for (int t = 0; t < NK; ++t) {
    if (t > 0) {
      if (t < NK - 1) { asm volatile("s_waitcnt vmcnt(6)" ::: "memory"); }
      else            { asm volatile("s_waitcnt vmcnt(0)" ::: "memory"); }
      SCHED0();
      __builtin_amdgcn_s_barrier();
      SCHED0();
    }
    const char* Ac = Abuf[t & 1];
    const char* Bc = Braw[t & 1];
    unsigned sv[4];
    #pragma unroll
    for (int fn = 0; fn < 4; ++fn) {
      int n = wc * 64 + fn * 16 + r15;
      sv[fn] = *(const unsigned*)((const char*)sScl + n * 72 + t * 4);
    }
    #pragma unroll
    for (int kq = 0; kq < 2; ++kq) {
      int kc = kq * 4 + kg;
      bf16x8 bfr[4];
      #pragma unroll
      for (int fn = 0; fn < 4; ++fn) {
        int n = wc * 64 + fn * 16 + r15;
        int4 raw = *(const int4*)(Bc + n * 128 + ((kc ^ (n & 7)) << 4));
        int s = kq ? (int)(sv[fn] >> 16) : (int)(sv[fn] & 0xFFFF);
        bfr[fn] = decode_frag(raw, s);
      }
      #pragma unroll
      for (int fm = 0; fm < 2; ++fm) {
        int m = wr * 32 + fm * 16 + r15;
        bf16x8 af = *(const bf16x8*)(Ac + m * 128 + ((kc ^ (m & 7)) << 4));
        #pragma unroll
        for (int fn = 0; fn < 4; ++fn)
          acc[fm][fn] = __builtin_amdgcn_mfma_f32_16x16x32_bf16(af, bfr[fn], acc[fm][fn], 0, 0, 0);
      }
    }
    if (t + 2 < NK) {
      asm volatile("s_waitcnt lgkmcnt(0)" ::: "memory");
      SCHED0();
      __builtin_amdgcn_s_barrier();
      SCHED0();
      char* An = Abuf[t & 1];
      char* Bn = Braw[t & 1];
      #pragma unroll
      for (int q = 0; q < 2; ++q)
        gll16((const char*)act + aOff[q] + (t + 2) * 128, An + (w * 16 + q * 8) * 128);
      #pragma unroll
      for (int q = 0; q < 4; ++q)
        gll16(bSrc[q] + (t + 2) * 128, Bn + (w * 32 + q * 8) * 128);
    }
  }

  #pragma unroll
  for (int fm = 0; fm < 2; ++fm) {
    #pragma unroll
    for (int rg = 0; rg < 4; ++rg) {
      int mloc = wr * 32 + fm * 16 + kg * 4 + rg;
      if (mloc < n_valid) {
        int entry = s_tok[mloc];
        int t2 = entry >> 3, j = entry & 7;
        size_t slot = (size_t)t2 * kk + j;
        #pragma unroll
        for (int fn = 0; fn < 4; ++fn) {
          int h = hbase + wc * 64 + fn * 16 + r15;
          partial[slot * HH + h] = (__bf16)acc[fm][fn][rg];
        }
      }
    }
  }
}

// ---------------- combine ----------------
__global__ void combine_kernel(const __bf16* __restrict__ partial, const float* __restrict__ route,
                               const float* __restrict__ dbias, const int* __restrict__ dk,
                               float* __restrict__ out, int E) {
  int t = blockIdx.y;
  int h = blockIdx.x * 256 + threadIdx.x;
  int kk = *dk; if (kk > KMAX) kk = KMAX; if (kk < 1) kk = 1;
  float s = 0.f;
  for (int j = 0; j < kk; ++j) s += (float)partial[((size_t)t * kk + j) * HH + h];
  for (int e = 0; e < E; ++e) s += route[t * E + e] * dbias[(size_t)e * HH + h];
  out[(size_t)t * HH + h] = s;
}

extern "C" void kernel_launch(void* const* d_in, const int* in_sizes, int n_in,
                              void* d_out, int out_size, void* d_ws, size_t ws_size,
                              hipStream_t stream) {
  const float* hs    = (const float*)d_in[0];
  const float* rl    = (const float*)d_in[1];
  const int*   gblk  = (const int*)d_in[2];
  const int*   gscl  = (const int*)d_in[3];
  const float* gbias = (const float*)d_in[4];
  const int*   ublk  = (const int*)d_in[5];
  const int*   uscl  = (const int*)d_in[6];
  const float* ubias = (const float*)d_in[7];
  const int*   dblk  = (const int*)d_in[8];
  const int*   dscl  = (const int*)d_in[9];
  const float* dbias = (const float*)d_in[10];
  const int*   dk    = (const int*)d_in[11];

  long s0 = in_sizes[0], s1 = in_sizes[1], s2 = in_sizes[2], s4 = in_sizes[4];
  int H = (int)(2 * s2 / s4);       // = 1024
  int T = (int)(s0 / H);            // = 1024
  int E = (int)(s1 / T);            // = 8

  char* w = (char*)d_ws;
  auto alloc = [&](size_t bytes) { char* p = w; w += (bytes + 255) & ~size_t(255); return p; };
  float*  route   = (float*)alloc(sizeof(float) * (size_t)T * E);
  int*    tidx    = (int*)  alloc(sizeof(int)   * (size_t)T * KMAX);
  float*  twp     = (float*)alloc(sizeof(float) * (size_t)T * KMAX);
  int*    counts  = (int*)  alloc(sizeof(int)   * (size_t)E);
  int*    lists   = (int*)  alloc(sizeof(int)   * (size_t)E * T);
  int*    tabGU   = (int*)  alloc(sizeof(int)   * GU_TILES);
  int*    tabDN   = (int*)  alloc(sizeof(int)   * DN_TILES);
  __bf16* hsb     = (__bf16*)alloc(sizeof(__bf16) * (size_t)T * HH);
  __bf16* act     = (__bf16*)alloc(sizeof(__bf16) * (size_t)T * KMAX * II);
  __bf16* partial = (__bf16*)alloc(sizeof(__bf16) * (size_t)T * KMAX * HH);

  routing_kernel<<<dim3((T + 255) / 256), 256, 0, stream>>>(rl, dk, T, E, route, tidx, twp);
  build_lists<<<dim3(E), 64, 0, stream>>>(tidx, dk, T, lists, counts);
  build_tiles<<<dim3(1), 64, 0, stream>>>(counts, E, tabGU, tabDN);
  convert_hs<<<dim3((T * HH / 8 + 255) / 256), 256, 0, stream>>>(hs, hsb, T * HH / 8);
  gemm_gate_up<<<dim3(GU_TILES, II / 64), 256, 0, stream>>>(
      hsb, gblk, gscl, gbias, ublk, uscl, ubias, lists, counts, twp, dk, tabGU, act, T);
  gemm_down<<<dim3(DN_TILES, HH / 128), 256, 0, stream>>>(
      act, dblk, dscl, lists, counts, dk, tabDN, partial, T);
  combine_kernel<<<dim3(HH / 256, T), 256, 0, stream>>>(partial, route, dbias, dk, (float*)d_out, E);
}